// Round 1
// baseline (6327.066 us; speedup 1.0000x reference)
//
#include <hip/hip_runtime.h>
#include <stdint.h>

#define Bv 64
#define Tv 512
#define Dv 256
#define Uv 512

typedef __attribute__((ext_vector_type(8))) __bf16 bf16x8;
typedef __attribute__((ext_vector_type(8))) short short8;
typedef __attribute__((ext_vector_type(4))) float f32x4;

// Barrier state: device globals (zero-init at module load). Counters are never
// reset; each WG tracks its own launch generation, barrier target = 64*gen.
// This is graph-replay safe (every execution increments gen exactly once).
__device__ unsigned int g_ctr[4 * Tv];
__device__ unsigned int g_gen[256];

__device__ __forceinline__ unsigned int f2bf_bits(float x) {
    unsigned int u = __float_as_uint(x);
    return (u + 0x7fffu + ((u >> 16) & 1u)) >> 16;   // RNE truncate to bf16
}
__device__ __forceinline__ float bfbits2f(unsigned int b) {
    return __uint_as_float(b << 16);
}

extern "C" __global__ void __launch_bounds__(256, 1)
noglstm_kernel(const float* __restrict__ x,
               const float* __restrict__ w_xi, const float* __restrict__ w_xf, const float* __restrict__ w_xc,
               const float* __restrict__ w_hi, const float* __restrict__ w_hf, const float* __restrict__ w_hc,
               const float* __restrict__ b_i, const float* __restrict__ b_f, const float* __restrict__ b_c,
               const float* __restrict__ h0, const float* __restrict__ c0,
               float* __restrict__ out)
{
    // LDS: h fragments (hi/lo bf16, A-operand layout), x fragments, partials.
    __shared__ uint4 hHi[16 * 64], hLo[16 * 64];   // 16 KB + 16 KB
    __shared__ uint4 xHi[8 * 64],  xLo[8 * 64];    //  8 KB +  8 KB
    __shared__ f32x4 partLds[4 * 64];              //  4 KB
    __shared__ float cTile[128];                   // persistent c state [16r x 8u]
    __shared__ float biasLds[24];
    __shared__ unsigned int genLds;

    const int tid  = threadIdx.x;
    const int wg   = blockIdx.x;
    const int g    = wg >> 6;          // row group 0..3 (16 batch rows each)
    const int col  = wg & 63;          // u-column group (8 u's each)
    const int r0   = g * 16;
    const int u0   = col * 8;
    const int wv   = tid >> 6;         // wave 0..3
    const int lane = tid & 63;
    const int nt   = wv & 1;           // n-tile: 0 = gates i|f, 1 = gate c|pad
    const int kh   = wv >> 1;          // k-half
    const int n    = lane & 15;        // tile column
    const int quad = lane >> 4;

    if (tid == 0) { unsigned v = g_gen[wg] + 1u; g_gen[wg] = v; genLds = v; }

    if (tid < 8)       biasLds[tid] = b_i[u0 + tid];
    else if (tid < 16) biasLds[tid] = b_f[u0 + tid - 8];
    else if (tid < 24) biasLds[tid] = b_c[u0 + tid - 16];
    if (tid < 128) cTile[tid] = c0[(size_t)(r0 + (tid >> 3)) * Uv + u0 + (tid & 7)];

    // ---- W fragments: gathered once into registers as bf16 hi/lo pairs ----
    // tile col -> gate/j:  nt0: c0..7 = gate i, c8..15 = gate f;  nt1: c0..7 = gate c, c8..15 dead
    int gate; bool dead;
    if (nt == 0) { gate = (n < 8) ? 0 : 1; dead = false; }
    else         { gate = 2;               dead = (n >= 8); }
    const int jcol = n & 7;
    const float* Wh = (gate == 0) ? w_hi : (gate == 1) ? w_hf : w_hc;
    const float* Wx = (gate == 0) ? w_xi : (gate == 1) ? w_xf : w_xc;
    const int ucol = u0 + jcol;

    bf16x8 whHiR[8], whLoR[8], wxHiR[4], wxLoR[4];
    #pragma unroll
    for (int i = 0; i < 8; ++i) {
        int kt = kh * 8 + i;
        short8 hi8, lo8;
        #pragma unroll
        for (int e = 0; e < 8; ++e) {
            int k = kt * 32 + quad * 8 + e;     // B[k][n] fragment: k = kt*32 + quad*8 + e
            float w = dead ? 0.f : Wh[(size_t)k * Uv + ucol];
            unsigned int hb = f2bf_bits(w);
            unsigned int lb = dead ? 0u : f2bf_bits(w - bfbits2f(hb));
            hi8[e] = (short)hb; lo8[e] = (short)lb;
        }
        whHiR[i] = __builtin_bit_cast(bf16x8, hi8);
        whLoR[i] = __builtin_bit_cast(bf16x8, lo8);
    }
    #pragma unroll
    for (int i = 0; i < 4; ++i) {
        int kt = kh * 4 + i;
        short8 hi8, lo8;
        #pragma unroll
        for (int e = 0; e < 8; ++e) {
            int k = kt * 32 + quad * 8 + e;
            float w = dead ? 0.f : Wx[(size_t)k * Uv + ucol];
            unsigned int hb = f2bf_bits(w);
            unsigned int lb = dead ? 0u : f2bf_bits(w - bfbits2f(hb));
            hi8[e] = (short)hb; lo8[e] = (short)lb;
        }
        wxHiR[i] = __builtin_bit_cast(bf16x8, hi8);
        wxLoR[i] = __builtin_bit_cast(bf16x8, lo8);
    }

    // stage 8 contiguous fp32 -> bf16 hi/lo packed 16B each
    auto stage8 = [&](const float* p, uint4* dHi, uint4* dLo) {
        f32x4 a = *(const f32x4*)p;
        f32x4 b = *(const f32x4*)(p + 4);
        float v[8] = {a[0], a[1], a[2], a[3], b[0], b[1], b[2], b[3]};
        unsigned int hb[8], lb[8];
        #pragma unroll
        for (int e = 0; e < 8; ++e) {
            hb[e] = f2bf_bits(v[e]);
            lb[e] = f2bf_bits(v[e] - bfbits2f(hb[e]));
        }
        uint4 H = make_uint4(hb[0] | (hb[1] << 16), hb[2] | (hb[3] << 16),
                             hb[4] | (hb[5] << 16), hb[6] | (hb[7] << 16));
        uint4 L = make_uint4(lb[0] | (lb[1] << 16), lb[2] | (lb[3] << 16),
                             lb[4] | (lb[5] << 16), lb[6] | (lb[7] << 16));
        *dHi = H; *dLo = L;
    };

    // prefetch x fragments for t = 0
    #pragma unroll
    for (int i = 0; i < 2; ++i) {
        int unit = tid + 256 * i;                 // 0..511 = (kt 0..7) x (lane 0..63)
        int kt = unit >> 6, l = unit & 63;
        int m = l & 15, q = l >> 4;
        const float* p = x + ((size_t)(r0 + m) * Tv + 0) * Dv + kt * 32 + q * 8;
        stage8(p, &xHi[kt * 64 + l], &xLo[kt * 64 + l]);
    }
    __syncthreads();

    const unsigned int target = 64u * genLds;

    for (int t = 0; t < Tv; ++t) {
        // ---- stage h(t-1) fragments (A layout: A[m=lane&15][k=quad*8+e]) ----
        const float* hsrc = (t == 0) ? h0 : (out + (size_t)(t - 1) * Uv);
        const size_t hstr = (t == 0) ? (size_t)Uv : (size_t)Tv * Uv;
        #pragma unroll
        for (int i = 0; i < 4; ++i) {
            int unit = tid + 256 * i;             // 0..1023 = (kt 0..15) x (lane)
            int kt = unit >> 6, l = unit & 63;
            int m = l & 15, q = l >> 4;
            const float* p = hsrc + (size_t)(r0 + m) * hstr + kt * 32 + q * 8;
            stage8(p, &hHi[kt * 64 + l], &hLo[kt * 64 + l]);
        }
        __syncthreads();

        // ---- MFMA: acc = x_t @ Wx + h @ Wh  (bf16x2: hi*hi + hi*lo + lo*hi) ----
        f32x4 acc = {0.f, 0.f, 0.f, 0.f};
        #pragma unroll
        for (int i = 0; i < 4; ++i) {
            int kt = kh * 4 + i;
            bf16x8 aH = *(const bf16x8*)&xHi[kt * 64 + lane];
            bf16x8 aL = *(const bf16x8*)&xLo[kt * 64 + lane];
            acc = __builtin_amdgcn_mfma_f32_16x16x32_bf16(aH, wxHiR[i], acc, 0, 0, 0);
            acc = __builtin_amdgcn_mfma_f32_16x16x32_bf16(aH, wxLoR[i], acc, 0, 0, 0);
            acc = __builtin_amdgcn_mfma_f32_16x16x32_bf16(aL, wxHiR[i], acc, 0, 0, 0);
        }
        #pragma unroll
        for (int i = 0; i < 8; ++i) {
            int kt = kh * 8 + i;
            bf16x8 aH = *(const bf16x8*)&hHi[kt * 64 + lane];
            bf16x8 aL = *(const bf16x8*)&hLo[kt * 64 + lane];
            acc = __builtin_amdgcn_mfma_f32_16x16x32_bf16(aH, whHiR[i], acc, 0, 0, 0);
            acc = __builtin_amdgcn_mfma_f32_16x16x32_bf16(aH, whLoR[i], acc, 0, 0, 0);
            acc = __builtin_amdgcn_mfma_f32_16x16x32_bf16(aL, whHiR[i], acc, 0, 0, 0);
        }
        partLds[wv * 64 + lane] = acc;
        __syncthreads();

        // ---- epilogue (waves 0-1) || x(t+1) prefetch (waves 2-3) ----
        if (tid < 128) {
            int r = tid >> 3, jj = tid & 7;
            int lidx = (r >> 2) * 16;             // D layout: col = lane&15, row = quad*4+reg
            int reg = r & 3;
            const float* pf = (const float*)partLds;
            float pi = pf[((0 * 64 + lidx + jj) << 2) + reg] + pf[((2 * 64 + lidx + jj) << 2) + reg] + biasLds[jj];
            float pF = pf[((0 * 64 + lidx + jj + 8) << 2) + reg] + pf[((2 * 64 + lidx + jj + 8) << 2) + reg] + biasLds[8 + jj];
            float pc = pf[((1 * 64 + lidx + jj) << 2) + reg] + pf[((3 * 64 + lidx + jj) << 2) + reg] + biasLds[16 + jj];
            float iv = 1.f / (1.f + __expf(-pi));
            float fv = 1.f / (1.f + __expf(-pF));
            float cin = tanhf(pc);
            float cn = fv * cTile[tid] + iv * cin;
            cTile[tid] = cn;
            out[((size_t)(r0 + r) * Tv + t) * Uv + u0 + jj] = tanhf(cn);
        } else if (t + 1 < Tv) {
            #pragma unroll
            for (int i = 0; i < 4; ++i) {
                int unit = (tid - 128) + 128 * i; // 0..511
                int kt = unit >> 6, l = unit & 63;
                int m = l & 15, q = l >> 4;
                const float* p = x + ((size_t)(r0 + m) * Tv + (t + 1)) * Dv + kt * 32 + q * 8;
                stage8(p, &xHi[kt * 64 + l], &xLo[kt * 64 + l]);
            }
        }
        __syncthreads();

        // ---- group barrier: 64 WGs sharing this row-group ----
        if (t + 1 < Tv) {
            if (tid == 0) {
                __hip_atomic_fetch_add(&g_ctr[g * Tv + t], 1u, __ATOMIC_RELEASE, __HIP_MEMORY_SCOPE_AGENT);
                unsigned int spins = 0;
                while (__hip_atomic_load(&g_ctr[g * Tv + t], __ATOMIC_RELAXED, __HIP_MEMORY_SCOPE_AGENT) < target) {
                    __builtin_amdgcn_s_sleep(1);
                    if (++spins > (1u << 20)) break;   // bounded: fail loud, never hang
                }
                __threadfence();                        // acquire: invalidate stale L1/L2
            }
            __syncthreads();
        }
    }
}

extern "C" void kernel_launch(void* const* d_in, const int* in_sizes, int n_in,
                              void* d_out, int out_size, void* d_ws, size_t ws_size,
                              hipStream_t stream) {
    (void)in_sizes; (void)n_in; (void)out_size; (void)d_ws; (void)ws_size;
    noglstm_kernel<<<dim3(256), dim3(256), 0, stream>>>(
        (const float*)d_in[0],
        (const float*)d_in[1], (const float*)d_in[2], (const float*)d_in[3],
        (const float*)d_in[4], (const float*)d_in[5], (const float*)d_in[6],
        (const float*)d_in[7], (const float*)d_in[8], (const float*)d_in[9],
        (const float*)d_in[10], (const float*)d_in[11],
        (float*)d_out);
}

// Round 2
// 2882.388 us; speedup vs baseline: 2.1951x; 2.1951x over previous
//
#include <hip/hip_runtime.h>
#include <stdint.h>

#define Bv 64
#define Tv 512
#define Dv 256
#define Uv 512

typedef __attribute__((ext_vector_type(8))) __bf16 bf16x8;
typedef __attribute__((ext_vector_type(8))) short short8;
typedef __attribute__((ext_vector_type(4))) float f32x4;

// Persistent device globals (zero at module load; harness never poisons these).
// g_ctr: per-(group,t) arrival counters, never reset; target = 64 * generation.
// g_hbuf: double-buffered h exchange, packed bf16 hi|lo per element, exchanged
// via agent-scope (sc0 sc1) atomics -> coherent at LLC, NO cache fences needed.
__device__ unsigned int g_ctr[4 * Tv];
__device__ unsigned int g_gen[256];
__device__ unsigned int g_hbuf[2 * Bv * Uv];

__device__ __forceinline__ unsigned int f2bf_bits(float x) {
    unsigned int u = __float_as_uint(x);
    return (u + 0x7fffu + ((u >> 16) & 1u)) >> 16;   // RNE truncate to bf16
}
__device__ __forceinline__ float bfbits2f(unsigned int b) {
    return __uint_as_float(b << 16);
}
__device__ __forceinline__ float fast_sigmoid(float x) {
    return __builtin_amdgcn_rcpf(1.f + __expf(-x));
}
__device__ __forceinline__ float fast_tanh(float x) {
    float ax = fabsf(x);
    float t  = __expf(-2.f * ax);
    float r  = (1.f - t) * __builtin_amdgcn_rcpf(1.f + t);
    return x < 0.f ? -r : r;
}

extern "C" __global__ void __launch_bounds__(256, 1)
noglstm_kernel(const float* __restrict__ x,
               const float* __restrict__ w_xi, const float* __restrict__ w_xf, const float* __restrict__ w_xc,
               const float* __restrict__ w_hi, const float* __restrict__ w_hf, const float* __restrict__ w_hc,
               const float* __restrict__ b_i, const float* __restrict__ b_f, const float* __restrict__ b_c,
               const float* __restrict__ h0, const float* __restrict__ c0,
               float* __restrict__ out)
{
    __shared__ uint4 hHi[16 * 64], hLo[16 * 64];   // 16 KB + 16 KB
    __shared__ uint4 xHi[8 * 64],  xLo[8 * 64];    //  8 KB +  8 KB
    __shared__ f32x4 partLds[4 * 64];              //  4 KB
    __shared__ float cTile[128];                   // persistent c state [16r x 8u]
    __shared__ float biasLds[24];
    __shared__ unsigned int genLds;

    const int tid  = threadIdx.x;
    const int wg   = blockIdx.x;
    const int g    = wg >> 6;          // row group 0..3 (16 batch rows each)
    const int col  = wg & 63;          // u-column group (8 u's each)
    const int r0   = g * 16;
    const int u0   = col * 8;
    const int wv   = tid >> 6;         // wave 0..3
    const int lane = tid & 63;
    const int nt   = wv & 1;           // n-tile: 0 = gates i|f, 1 = gate c|pad
    const int kh   = wv >> 1;          // k-half
    const int n    = lane & 15;        // tile column
    const int quad = lane >> 4;

    if (tid == 0) { unsigned v = g_gen[wg] + 1u; g_gen[wg] = v; genLds = v; }

    if (tid < 8)       biasLds[tid] = b_i[u0 + tid];
    else if (tid < 16) biasLds[tid] = b_f[u0 + tid - 8];
    else if (tid < 24) biasLds[tid] = b_c[u0 + tid - 16];
    if (tid < 128) cTile[tid] = c0[(size_t)(r0 + (tid >> 3)) * Uv + u0 + (tid & 7)];

    // ---- W fragments: gathered once into registers as bf16 hi/lo pairs ----
    int gate; bool dead;
    if (nt == 0) { gate = (n < 8) ? 0 : 1; dead = false; }
    else         { gate = 2;               dead = (n >= 8); }
    const int jcol = n & 7;
    const float* Wh = (gate == 0) ? w_hi : (gate == 1) ? w_hf : w_hc;
    const float* Wx = (gate == 0) ? w_xi : (gate == 1) ? w_xf : w_xc;
    const int ucol = u0 + jcol;

    bf16x8 whHiR[8], whLoR[8], wxHiR[4], wxLoR[4];
    #pragma unroll
    for (int i = 0; i < 8; ++i) {
        int kt = kh * 8 + i;
        short8 hi8, lo8;
        #pragma unroll
        for (int e = 0; e < 8; ++e) {
            int k = kt * 32 + quad * 8 + e;
            float w = dead ? 0.f : Wh[(size_t)k * Uv + ucol];
            unsigned int hb = f2bf_bits(w);
            unsigned int lb = dead ? 0u : f2bf_bits(w - bfbits2f(hb));
            hi8[e] = (short)hb; lo8[e] = (short)lb;
        }
        whHiR[i] = __builtin_bit_cast(bf16x8, hi8);
        whLoR[i] = __builtin_bit_cast(bf16x8, lo8);
    }
    #pragma unroll
    for (int i = 0; i < 4; ++i) {
        int kt = kh * 4 + i;
        short8 hi8, lo8;
        #pragma unroll
        for (int e = 0; e < 8; ++e) {
            int k = kt * 32 + quad * 8 + e;
            float w = dead ? 0.f : Wx[(size_t)k * Uv + ucol];
            unsigned int hb = f2bf_bits(w);
            unsigned int lb = dead ? 0u : f2bf_bits(w - bfbits2f(hb));
            hi8[e] = (short)hb; lo8[e] = (short)lb;
        }
        wxHiR[i] = __builtin_bit_cast(bf16x8, hi8);
        wxLoR[i] = __builtin_bit_cast(bf16x8, lo8);
    }

    // stage 8 contiguous fp32 -> bf16 hi/lo packed 16B each (x and h0 path)
    auto stage8 = [&](const float* p, uint4* dHi, uint4* dLo) {
        f32x4 a = *(const f32x4*)p;
        f32x4 b = *(const f32x4*)(p + 4);
        float v[8] = {a[0], a[1], a[2], a[3], b[0], b[1], b[2], b[3]};
        unsigned int hb[8], lb[8];
        #pragma unroll
        for (int e = 0; e < 8; ++e) {
            hb[e] = f2bf_bits(v[e]);
            lb[e] = f2bf_bits(v[e] - bfbits2f(hb[e]));
        }
        *dHi = make_uint4(hb[0] | (hb[1] << 16), hb[2] | (hb[3] << 16),
                          hb[4] | (hb[5] << 16), hb[6] | (hb[7] << 16));
        *dLo = make_uint4(lb[0] | (lb[1] << 16), lb[2] | (lb[3] << 16),
                          lb[4] | (lb[5] << 16), lb[6] | (lb[7] << 16));
    };

    // prefetch x fragments for t = 0 (all 256 threads)
    #pragma unroll
    for (int i = 0; i < 2; ++i) {
        int unit = tid + 256 * i;
        int kt = unit >> 6, l = unit & 63;
        int m = l & 15, q = l >> 4;
        const float* p = x + ((size_t)(r0 + m) * Tv + 0) * Dv + kt * 32 + q * 8;
        stage8(p, &xHi[kt * 64 + l], &xLo[kt * 64 + l]);
    }
    __syncthreads();

    const unsigned int target = 64u * genLds;

    for (int t = 0; t < Tv; ++t) {
        const bool packed = (t != 0);
        unsigned long long hw[16];

        // ---- issue h(t-1) loads first (uncached, from coherent point) ----
        if (packed) {
            const unsigned int* hb = g_hbuf + (unsigned)((t - 1) & 1) * (Bv * Uv);
            #pragma unroll
            for (int i = 0; i < 4; ++i) {
                int unit = tid + 256 * i;
                int kt = unit >> 6, l = unit & 63;
                int m = l & 15, q = l >> 4;
                const unsigned long long* p =
                    (const unsigned long long*)(hb + (r0 + m) * Uv + kt * 32 + q * 8);
                #pragma unroll
                for (int j = 0; j < 4; ++j)
                    hw[i * 4 + j] = __hip_atomic_load(p + j, __ATOMIC_RELAXED,
                                                      __HIP_MEMORY_SCOPE_AGENT);
            }
        }

        // ---- x-part MFMA overlaps the h load latency ----
        f32x4 accX = {0.f, 0.f, 0.f, 0.f};
        #pragma unroll
        for (int i = 0; i < 4; ++i) {
            int kt = kh * 4 + i;
            bf16x8 aH = *(const bf16x8*)&xHi[kt * 64 + lane];
            bf16x8 aL = *(const bf16x8*)&xLo[kt * 64 + lane];
            accX = __builtin_amdgcn_mfma_f32_16x16x32_bf16(aH, wxHiR[i], accX, 0, 0, 0);
            accX = __builtin_amdgcn_mfma_f32_16x16x32_bf16(aH, wxLoR[i], accX, 0, 0, 0);
            accX = __builtin_amdgcn_mfma_f32_16x16x32_bf16(aL, wxHiR[i], accX, 0, 0, 0);
        }

        // ---- stage h fragments into LDS ----
        if (packed) {
            #pragma unroll
            for (int i = 0; i < 4; ++i) {
                int unit = tid + 256 * i;
                int kt = unit >> 6, l = unit & 63;
                short8 hi8, lo8;
                #pragma unroll
                for (int j = 0; j < 4; ++j) {
                    unsigned long long w = hw[i * 4 + j];
                    unsigned int d0 = (unsigned int)w;
                    unsigned int d1 = (unsigned int)(w >> 32);
                    hi8[2 * j]     = (short)(d0 >> 16);
                    lo8[2 * j]     = (short)(d0 & 0xffffu);
                    hi8[2 * j + 1] = (short)(d1 >> 16);
                    lo8[2 * j + 1] = (short)(d1 & 0xffffu);
                }
                hHi[kt * 64 + l] = __builtin_bit_cast(uint4, hi8);
                hLo[kt * 64 + l] = __builtin_bit_cast(uint4, lo8);
            }
        } else {
            #pragma unroll
            for (int i = 0; i < 4; ++i) {
                int unit = tid + 256 * i;
                int kt = unit >> 6, l = unit & 63;
                int m = l & 15, q = l >> 4;
                const float* p = h0 + (size_t)(r0 + m) * Uv + kt * 32 + q * 8;
                stage8(p, &hHi[kt * 64 + l], &hLo[kt * 64 + l]);
            }
        }
        __syncthreads();

        // ---- h-part MFMA: two independent chains ----
        f32x4 accH0 = {0.f, 0.f, 0.f, 0.f}, accH1 = {0.f, 0.f, 0.f, 0.f};
        #pragma unroll
        for (int i = 0; i < 8; ++i) {
            int kt = kh * 8 + i;
            bf16x8 aH = *(const bf16x8*)&hHi[kt * 64 + lane];
            bf16x8 aL = *(const bf16x8*)&hLo[kt * 64 + lane];
            if (i < 4) {
                accH0 = __builtin_amdgcn_mfma_f32_16x16x32_bf16(aH, whHiR[i], accH0, 0, 0, 0);
                accH0 = __builtin_amdgcn_mfma_f32_16x16x32_bf16(aH, whLoR[i], accH0, 0, 0, 0);
                accH0 = __builtin_amdgcn_mfma_f32_16x16x32_bf16(aL, whHiR[i], accH0, 0, 0, 0);
            } else {
                accH1 = __builtin_amdgcn_mfma_f32_16x16x32_bf16(aH, whHiR[i], accH1, 0, 0, 0);
                accH1 = __builtin_amdgcn_mfma_f32_16x16x32_bf16(aH, whLoR[i], accH1, 0, 0, 0);
                accH1 = __builtin_amdgcn_mfma_f32_16x16x32_bf16(aL, whHiR[i], accH1, 0, 0, 0);
            }
        }
        f32x4 acc;
        acc[0] = accX[0] + accH0[0] + accH1[0];
        acc[1] = accX[1] + accH0[1] + accH1[1];
        acc[2] = accX[2] + accH0[2] + accH1[2];
        acc[3] = accX[3] + accH0[3] + accH1[3];
        partLds[wv * 64 + lane] = acc;
        __syncthreads();

        // ---- epilogue (waves 0-1) || x(t+1) prefetch (waves 2-3) ----
        if (tid < 128) {
            int r = tid >> 3, jj = tid & 7;
            int lidx = (r >> 2) * 16;             // D layout: col = lane&15, row = quad*4+reg
            int reg = r & 3;
            const float* pf = (const float*)partLds;
            float pi = pf[((0 * 64 + lidx + jj) << 2) + reg] + pf[((2 * 64 + lidx + jj) << 2) + reg] + biasLds[jj];
            float pF = pf[((0 * 64 + lidx + jj + 8) << 2) + reg] + pf[((2 * 64 + lidx + jj + 8) << 2) + reg] + biasLds[8 + jj];
            float pc = pf[((1 * 64 + lidx + jj) << 2) + reg] + pf[((3 * 64 + lidx + jj) << 2) + reg] + biasLds[16 + jj];
            float iv  = fast_sigmoid(pi);
            float fv  = fast_sigmoid(pF);
            float cin = fast_tanh(pc);
            float cn  = fv * cTile[tid] + iv * cin;
            cTile[tid] = cn;
            float hn = fast_tanh(cn);
            out[((size_t)(r0 + r) * Tv + t) * Uv + u0 + jj] = hn;   // cached store, flushed at kernel end
            unsigned int hbb = f2bf_bits(hn);
            unsigned int lbb = f2bf_bits(hn - bfbits2f(hbb));
            unsigned int* dst = g_hbuf + (unsigned)(t & 1) * (Bv * Uv) + (r0 + r) * Uv + u0 + jj;
            __hip_atomic_store(dst, (hbb << 16) | lbb, __ATOMIC_RELAXED,
                               __HIP_MEMORY_SCOPE_AGENT);
        } else if (t + 1 < Tv) {
            #pragma unroll
            for (int i = 0; i < 4; ++i) {
                int unit = (tid - 128) + 128 * i;
                int kt = unit >> 6, l = unit & 63;
                int m = l & 15, q = l >> 4;
                const float* p = x + ((size_t)(r0 + m) * Tv + (t + 1)) * Dv + kt * 32 + q * 8;
                stage8(p, &xHi[kt * 64 + l], &xLo[kt * 64 + l]);
            }
        }
        __syncthreads();   // drains vmcnt(0): all h stores are at the coherent point

        // ---- group barrier: relaxed atomics only, NO cache fences ----
        if (t + 1 < Tv) {
            if (tid == 0) {
                __hip_atomic_fetch_add(&g_ctr[g * Tv + t], 1u, __ATOMIC_RELAXED,
                                       __HIP_MEMORY_SCOPE_AGENT);
                unsigned int spins = 0;
                while (__hip_atomic_load(&g_ctr[g * Tv + t], __ATOMIC_RELAXED,
                                         __HIP_MEMORY_SCOPE_AGENT) < target) {
                    if (++spins > (1u << 21)) break;   // bounded: fail loud, never hang
                }
            }
            __syncthreads();
        }
    }
}

extern "C" void kernel_launch(void* const* d_in, const int* in_sizes, int n_in,
                              void* d_out, int out_size, void* d_ws, size_t ws_size,
                              hipStream_t stream) {
    (void)in_sizes; (void)n_in; (void)out_size; (void)d_ws; (void)ws_size;
    noglstm_kernel<<<dim3(256), dim3(256), 0, stream>>>(
        (const float*)d_in[0],
        (const float*)d_in[1], (const float*)d_in[2], (const float*)d_in[3],
        (const float*)d_in[4], (const float*)d_in[5], (const float*)d_in[6],
        (const float*)d_in[7], (const float*)d_in[8], (const float*)d_in[9],
        (const float*)d_in[10], (const float*)d_in[11],
        (float*)d_out);
}

// Round 3
// 2500.860 us; speedup vs baseline: 2.5300x; 1.1526x over previous
//
#include <hip/hip_runtime.h>
#include <stdint.h>

#define Bv 64
#define Tv 512
#define Dv 256
#define Uv 512
#define WPG 32   // workgroups per row-group; each owns 16 u-cols x 3 gates

typedef __attribute__((ext_vector_type(8))) __bf16 bf16x8;
typedef __attribute__((ext_vector_type(8))) short short8;
typedef __attribute__((ext_vector_type(4))) float f32x4;

// Persistent device globals (zero at module load; never poisoned by harness).
// g_flag[g*32+c]: epoch flag = (gen-1)*512 + (t+1) after producer c of group g
//   finished step t. Monotonic across launches -> graph-replay safe.
// g_hbuf: double-buffered h exchange, 1 dword/elem = bf16 hi<<16 | bf16 lo,
//   written/read with agent-scope (sc0 sc1) atomics -> coherent at LLC,
//   zero cache-maintenance instructions anywhere in the loop.
__device__ unsigned int g_flag[4 * WPG];
__device__ unsigned int g_gen[4 * WPG];
__device__ unsigned int g_hbuf[2 * Bv * Uv];

__device__ __forceinline__ unsigned int f2bf_bits(float x) {
    unsigned int u = __float_as_uint(x);
    return (u + 0x7fffu + ((u >> 16) & 1u)) >> 16;   // RNE to bf16
}
__device__ __forceinline__ float bfbits2f(unsigned int b) {
    return __uint_as_float(b << 16);
}
__device__ __forceinline__ float fast_sigmoid(float x) {
    return __builtin_amdgcn_rcpf(1.f + __expf(-x));
}
__device__ __forceinline__ float fast_tanh(float x) {
    float ax = fabsf(x);
    float t  = __expf(-2.f * ax);
    float r  = (1.f - t) * __builtin_amdgcn_rcpf(1.f + t);
    return x < 0.f ? -r : r;
}

extern "C" __global__ void __launch_bounds__(256, 1)
noglstm_kernel(const float* __restrict__ x,
               const float* __restrict__ w_xi, const float* __restrict__ w_xf, const float* __restrict__ w_xc,
               const float* __restrict__ w_hi, const float* __restrict__ w_hf, const float* __restrict__ w_hc,
               const float* __restrict__ b_i, const float* __restrict__ b_f, const float* __restrict__ b_c,
               const float* __restrict__ h0, const float* __restrict__ c0,
               float* __restrict__ out)
{
    __shared__ uint4 hHi[16 * 64], hLo[16 * 64];   // 32 KB: h fragments hi/lo
    __shared__ uint4 xHi[8 * 64],  xLo[8 * 64];    // 16 KB: x fragments hi/lo
    __shared__ f32x4 partLds[12 * 64];             // 12 KB: 4 waves x 3 gates
    __shared__ float cTile[256];                   // persistent c state [16r x 16u]
    __shared__ float biasLds[48];
    __shared__ unsigned int baseLds;

    const int tid  = threadIdx.x;
    const int wg   = blockIdx.x;
    const int g    = wg >> 5;          // row group 0..3 (16 batch rows)
    const int c    = wg & 31;          // producer index within group
    const int r0   = g * 16;
    const int u0   = c * 16;
    const int wv   = tid >> 6;         // wave 0..3 = k-quarter
    const int lane = tid & 63;
    const int n    = lane & 15;
    const int quad = lane >> 4;
    const int kh   = wv;

    if (tid == 0) { unsigned v = g_gen[wg] + 1u; g_gen[wg] = v; baseLds = (v - 1u) * (unsigned)Tv; }
    if (tid < 16)      biasLds[tid]      = b_i[u0 + tid];
    else if (tid < 32) biasLds[tid]      = b_f[u0 + tid - 16];
    else if (tid < 48) biasLds[tid]      = b_c[u0 + tid - 32];
    cTile[tid] = c0[(size_t)(r0 + (tid >> 4)) * Uv + u0 + (tid & 15)];

    // ---- W fragments: registers, bf16 hi/lo split, gathered once ----
    const float* WhP[3] = {w_hi, w_hf, w_hc};
    const float* WxP[3] = {w_xi, w_xf, w_xc};
    const int ucol = u0 + n;

    bf16x8 whHiR[3][4], whLoR[3][4], wxHiR[3][2], wxLoR[3][2];
    #pragma unroll
    for (int nt = 0; nt < 3; ++nt) {
        #pragma unroll
        for (int i = 0; i < 4; ++i) {
            short8 hi8, lo8;
            #pragma unroll
            for (int e = 0; e < 8; ++e) {
                int k = (kh * 4 + i) * 32 + quad * 8 + e;
                float w = WhP[nt][(size_t)k * Uv + ucol];
                unsigned int hb = f2bf_bits(w);
                unsigned int lb = f2bf_bits(w - bfbits2f(hb));
                hi8[e] = (short)hb; lo8[e] = (short)lb;
            }
            whHiR[nt][i] = __builtin_bit_cast(bf16x8, hi8);
            whLoR[nt][i] = __builtin_bit_cast(bf16x8, lo8);
        }
        #pragma unroll
        for (int i = 0; i < 2; ++i) {
            short8 hi8, lo8;
            #pragma unroll
            for (int e = 0; e < 8; ++e) {
                int k = (kh * 2 + i) * 32 + quad * 8 + e;
                float w = WxP[nt][(size_t)k * Uv + ucol];
                unsigned int hb = f2bf_bits(w);
                unsigned int lb = f2bf_bits(w - bfbits2f(hb));
                hi8[e] = (short)hb; lo8[e] = (short)lb;
            }
            wxHiR[nt][i] = __builtin_bit_cast(bf16x8, hi8);
            wxLoR[nt][i] = __builtin_bit_cast(bf16x8, lo8);
        }
    }

    auto stage8 = [&](const float* p, uint4* dHi, uint4* dLo) {
        f32x4 a = *(const f32x4*)p;
        f32x4 b = *(const f32x4*)(p + 4);
        float v[8] = {a[0], a[1], a[2], a[3], b[0], b[1], b[2], b[3]};
        unsigned int hb[8], lb[8];
        #pragma unroll
        for (int e = 0; e < 8; ++e) {
            hb[e] = f2bf_bits(v[e]);
            lb[e] = f2bf_bits(v[e] - bfbits2f(hb[e]));
        }
        *dHi = make_uint4(hb[0] | (hb[1] << 16), hb[2] | (hb[3] << 16),
                          hb[4] | (hb[5] << 16), hb[6] | (hb[7] << 16));
        *dLo = make_uint4(lb[0] | (lb[1] << 16), lb[2] | (lb[3] << 16),
                          lb[4] | (lb[5] << 16), lb[6] | (lb[7] << 16));
    };

    // preload x fragments for t = 0 (512 units = 8 kt x 64 lanes)
    #pragma unroll
    for (int i = 0; i < 2; ++i) {
        int u = tid + 256 * i;
        int kt = u >> 6, ll = u & 63, mm = ll & 15, qq = ll >> 4;
        const float* p = x + ((size_t)(r0 + mm) * Tv + 0) * Dv + kt * 32 + qq * 8;
        stage8(p, &xHi[kt * 64 + ll], &xLo[kt * 64 + ll]);
    }
    __syncthreads();

    const unsigned int base = baseLds;
    // gather geometry: thread handles units (kt = wv + 4i, l = tid&63), i<4
    const int l = tid & 63, m = l & 15, q = l >> 4;
    // producer covering cols [kt*32 + q*8, +8) is c = 2*kt + (q>>1)
    const unsigned int cb = 2u * (unsigned)wv + (unsigned)(q >> 1);
    const unsigned int* fp = g_flag + g * WPG;

    for (int t = 0; t < Tv; ++t) {
        const bool packed = (t != 0);
        unsigned long long hw[16];

        if (packed) {
            // ---- fine-grained poll: only this thread's 4 producers ----
            const unsigned int E = base + (unsigned)t;
            unsigned int spins = 0;
            for (;;) {
                unsigned int v0 = __hip_atomic_load(&fp[cb],      __ATOMIC_RELAXED, __HIP_MEMORY_SCOPE_AGENT);
                unsigned int v1 = __hip_atomic_load(&fp[cb + 8],  __ATOMIC_RELAXED, __HIP_MEMORY_SCOPE_AGENT);
                unsigned int v2 = __hip_atomic_load(&fp[cb + 16], __ATOMIC_RELAXED, __HIP_MEMORY_SCOPE_AGENT);
                unsigned int v3 = __hip_atomic_load(&fp[cb + 24], __ATOMIC_RELAXED, __HIP_MEMORY_SCOPE_AGENT);
                if (v0 >= E && v1 >= E && v2 >= E && v3 >= E) break;
                __builtin_amdgcn_s_sleep(1);
                if (++spins > (1u << 20)) break;   // bounded: fail loud, never hang
            }
            __asm__ volatile("" ::: "memory");     // no hoisting of h loads above poll

            // ---- issue h(t-1) gather (uncached, served at coherent point) ----
            const unsigned int* hb = g_hbuf + (unsigned)((t - 1) & 1) * (Bv * Uv);
            #pragma unroll
            for (int i = 0; i < 4; ++i) {
                int kt = wv + 4 * i;
                const unsigned long long* p =
                    (const unsigned long long*)(hb + (r0 + m) * Uv + kt * 32 + q * 8);
                #pragma unroll
                for (int j = 0; j < 4; ++j)
                    hw[i * 4 + j] = __hip_atomic_load(p + j, __ATOMIC_RELAXED,
                                                      __HIP_MEMORY_SCOPE_AGENT);
            }
        } else {
            #pragma unroll
            for (int i = 0; i < 4; ++i) {
                int kt = wv + 4 * i;
                const float* p = h0 + (size_t)(r0 + m) * Uv + kt * 32 + q * 8;
                stage8(p, &hHi[kt * 64 + l], &hLo[kt * 64 + l]);
            }
        }

        // ---- x-part MFMA overlaps h gather latency ----
        f32x4 acc[3], accX[3];
        #pragma unroll
        for (int nt = 0; nt < 3; ++nt) { acc[nt] = f32x4{0.f,0.f,0.f,0.f}; accX[nt] = f32x4{0.f,0.f,0.f,0.f}; }
        #pragma unroll
        for (int i = 0; i < 2; ++i) {
            int kt = kh * 2 + i;
            bf16x8 aH = *(const bf16x8*)&xHi[kt * 64 + lane];
            bf16x8 aL = *(const bf16x8*)&xLo[kt * 64 + lane];
            #pragma unroll
            for (int nt = 0; nt < 3; ++nt) {
                accX[nt] = __builtin_amdgcn_mfma_f32_16x16x32_bf16(aH, wxHiR[nt][i], accX[nt], 0, 0, 0);
                accX[nt] = __builtin_amdgcn_mfma_f32_16x16x32_bf16(aH, wxLoR[nt][i], accX[nt], 0, 0, 0);
                accX[nt] = __builtin_amdgcn_mfma_f32_16x16x32_bf16(aL, wxHiR[nt][i], accX[nt], 0, 0, 0);
            }
        }

        // ---- unpack h -> LDS hi/lo planes ----
        if (packed) {
            #pragma unroll
            for (int i = 0; i < 4; ++i) {
                int kt = wv + 4 * i;
                short8 hi8, lo8;
                #pragma unroll
                for (int j = 0; j < 4; ++j) {
                    unsigned long long w = hw[i * 4 + j];
                    unsigned int d0 = (unsigned int)w;
                    unsigned int d1 = (unsigned int)(w >> 32);
                    hi8[2 * j]     = (short)(d0 >> 16);
                    lo8[2 * j]     = (short)(d0 & 0xffffu);
                    hi8[2 * j + 1] = (short)(d1 >> 16);
                    lo8[2 * j + 1] = (short)(d1 & 0xffffu);
                }
                hHi[kt * 64 + l] = __builtin_bit_cast(uint4, hi8);
                hLo[kt * 64 + l] = __builtin_bit_cast(uint4, lo8);
            }
        }
        __syncthreads();

        // ---- h-part MFMA: this wave's k-quarter, 3 gate columns ----
        #pragma unroll
        for (int i = 0; i < 4; ++i) {
            int kt = kh * 4 + i;
            bf16x8 aH = *(const bf16x8*)&hHi[kt * 64 + lane];
            bf16x8 aL = *(const bf16x8*)&hLo[kt * 64 + lane];
            #pragma unroll
            for (int nt = 0; nt < 3; ++nt) {
                acc[nt] = __builtin_amdgcn_mfma_f32_16x16x32_bf16(aH, whHiR[nt][i], acc[nt], 0, 0, 0);
                acc[nt] = __builtin_amdgcn_mfma_f32_16x16x32_bf16(aH, whLoR[nt][i], acc[nt], 0, 0, 0);
                acc[nt] = __builtin_amdgcn_mfma_f32_16x16x32_bf16(aL, whHiR[nt][i], acc[nt], 0, 0, 0);
            }
        }
        #pragma unroll
        for (int nt = 0; nt < 3; ++nt) {
            acc[nt][0] += accX[nt][0]; acc[nt][1] += accX[nt][1];
            acc[nt][2] += accX[nt][2]; acc[nt][3] += accX[nt][3];
            partLds[(wv * 3 + nt) * 64 + lane] = acc[nt];
        }
        __syncthreads();

        // ---- epilogue: one output element per thread ----
        {
            int r = tid >> 4, uu = tid & 15;
            int plane = (r >> 2) * 16 + uu;       // D layout: col=lane&15, row=quad*4+reg
            int reg = r & 3;
            const float* pf = (const float*)partLds;
            float pi = biasLds[uu], pF = biasLds[16 + uu], pc = biasLds[32 + uu];
            #pragma unroll
            for (int w = 0; w < 4; ++w) {
                pi += pf[((w * 3 + 0) * 64 + plane) * 4 + reg];
                pF += pf[((w * 3 + 1) * 64 + plane) * 4 + reg];
                pc += pf[((w * 3 + 2) * 64 + plane) * 4 + reg];
            }
            float iv  = fast_sigmoid(pi);
            float fv  = fast_sigmoid(pF);
            float cin = fast_tanh(pc);
            float cn  = fv * cTile[tid] + iv * cin;
            cTile[tid] = cn;
            float hn = fast_tanh(cn);
            out[((size_t)(r0 + r) * Tv + t) * Uv + u0 + uu] = hn;
            unsigned int hbb = f2bf_bits(hn);
            unsigned int lbb = f2bf_bits(hn - bfbits2f(hbb));
            __hip_atomic_store(g_hbuf + (unsigned)(t & 1) * (Bv * Uv) + (r0 + r) * Uv + u0 + uu,
                               (hbb << 16) | lbb, __ATOMIC_RELAXED, __HIP_MEMORY_SCOPE_AGENT);
        }
        __syncthreads();   // drains vmcnt(0): h stores are at the coherent point

        // ---- publish: single relaxed flag store, immediately ----
        if (tid == 0)
            __hip_atomic_store(&g_flag[g * WPG + c], base + (unsigned)t + 1u,
                               __ATOMIC_RELAXED, __HIP_MEMORY_SCOPE_AGENT);

        // ---- x prefetch for t+1: off the inter-WG critical path ----
        if (t + 1 < Tv) {
            #pragma unroll
            for (int i = 0; i < 2; ++i) {
                int u = tid + 256 * i;
                int kt = u >> 6, ll = u & 63, mm = ll & 15, qq = ll >> 4;
                const float* p = x + ((size_t)(r0 + mm) * Tv + (t + 1)) * Dv + kt * 32 + qq * 8;
                stage8(p, &xHi[kt * 64 + ll], &xLo[kt * 64 + ll]);
            }
        }
        __syncthreads();   // xLDS write (t+1) vs x-MFMA read hazard
    }
}

extern "C" void kernel_launch(void* const* d_in, const int* in_sizes, int n_in,
                              void* d_out, int out_size, void* d_ws, size_t ws_size,
                              hipStream_t stream) {
    (void)in_sizes; (void)n_in; (void)out_size; (void)d_ws; (void)ws_size;
    noglstm_kernel<<<dim3(128), dim3(256), 0, stream>>>(
        (const float*)d_in[0],
        (const float*)d_in[1], (const float*)d_in[2], (const float*)d_in[3],
        (const float*)d_in[4], (const float*)d_in[5], (const float*)d_in[6],
        (const float*)d_in[7], (const float*)d_in[8], (const float*)d_in[9],
        (const float*)d_in[10], (const float*)d_in[11],
        (float*)d_out);
}